// Round 13
// baseline (371.759 us; speedup 1.0000x reference)
//
#include <hip/hip_runtime.h>
#include <hip/hip_bf16.h>

constexpr int S   = 4096;
constexpr int D   = 2048;
constexpr int H   = 16;
constexpr int KVH = 4;
constexpr int HD  = 128;

using short8 = __attribute__((ext_vector_type(8))) short;
using f32x4  = __attribute__((ext_vector_type(4))) float;
using f32x16 = __attribute__((ext_vector_type(16))) float;

__device__ inline ushort f2bf(float f) {
  union { float f; unsigned u; } x{f};
  unsigned r = x.u + 0x7FFFu + ((x.u >> 16) & 1u);
  return (ushort)(r >> 16);
}
__device__ inline float bf2f(ushort h) {
  union { unsigned u; float f; } x{(unsigned)h << 16};
  return x.f;
}
// RNE pack: two floats -> bf16x2
__device__ inline unsigned pkbf(float a, float b) {
  union { float f; unsigned u; } xa{a}, xb{b};
  unsigned ra = xa.u + 0x7FFFu + ((xa.u >> 16) & 1u);
  unsigned rb = xb.u + 0x7FFFu + ((xb.u >> 16) & 1u);
#if __has_builtin(__builtin_amdgcn_perm)
  return __builtin_amdgcn_perm(rb, ra, 0x07060302u);
#else
  return (rb & 0xFFFF0000u) | (ra >> 16);
#endif
}
// truncating pack (1 VALU op): for P values in [0,1] feeding PV; ~0.2% downward bias
__device__ inline unsigned pkbf_t(float a, float b) {
  union { float f; unsigned u; } xa{a}, xb{b};
#if __has_builtin(__builtin_amdgcn_perm)
  return __builtin_amdgcn_perm(xb.u, xa.u, 0x07060302u);
#else
  return (xb.u & 0xFFFF0000u) | (xa.u >> 16);
#endif
}
__device__ inline float fast_exp2(float x) {
#if __has_builtin(__builtin_amdgcn_exp2f)
  return __builtin_amdgcn_exp2f(x);
#else
  return exp2f(x);
#endif
}

// lane i<->i+32 half exchange, one VALU op for TWO outputs:
// x = {a_lo, b_lo}, y = {a_hi, b_hi}  (verified correct by R6/R7/R9 harness passes)
__device__ inline void swap_half(unsigned a, unsigned b, unsigned& x, unsigned& y) {
#if __has_builtin(__builtin_amdgcn_permlane32_swap)
  using uint2v = __attribute__((ext_vector_type(2))) unsigned;
  uint2v r = __builtin_amdgcn_permlane32_swap(a, b, false, false);
  x = r[0]; y = r[1];
#else
  unsigned bx = __shfl_xor(b, 32), ax = __shfl_xor(a, 32);
  int p = (threadIdx.x & 63) >> 5;
  x = p ? bx : a;
  y = p ? b : ax;
#endif
}

__device__ inline void async_copy16(const ushort* g, ushort* l) {
  __builtin_amdgcn_global_load_lds(
      (const __attribute__((address_space(1))) unsigned int*)g,
      (__attribute__((address_space(3))) unsigned int*)l, 16, 0, 0);
}

// ---------------------------------------------------------------------------
// Fused fp32->bf16 convert (dst segments contiguous in ws)
// ---------------------------------------------------------------------------
constexpr size_t N_HID = (size_t)S * D;
constexpr size_t N_WQ  = (size_t)(H * HD) * D;
constexpr size_t N_WKV = (size_t)(KVH * HD) * D;
constexpr size_t C1_ = N_HID;
constexpr size_t C2_ = C1_ + N_WQ;
constexpr size_t C3_ = C2_ + N_WKV;
constexpr size_t C4_ = C3_ + N_WKV;
constexpr size_t C5_ = C4_ + N_WQ;

__global__ void cvt_all_kernel(const float* __restrict__ hid, const float* __restrict__ wq,
                               const float* __restrict__ wk, const float* __restrict__ wv,
                               const float* __restrict__ wo, ushort* __restrict__ dst) {
  size_t i = (size_t)blockIdx.x * blockDim.x + threadIdx.x;
  size_t off = i * 4;
  if (off >= C5_) return;
  const float* src;
  if      (off < C1_) src = hid + off;
  else if (off < C2_) src = wq + (off - C1_);
  else if (off < C3_) src = wk + (off - C2_);
  else if (off < C4_) src = wv + (off - C3_);
  else                src = wo + (off - C4_);
  float4 f = *(const float4*)src;
  ushort4 o;
  o.x = f2bf(f.x); o.y = f2bf(f.y); o.z = f2bf(f.z); o.w = f2bf(f.w);
  *(ushort4*)&dst[off] = o;
}

// ---------------------------------------------------------------------------
// bf16 MFMA GEMM tile (NT), m97 recipe — SINGLE-buffered (R3/R0 form; R7
// proved explicit dbuf regresses this structure, matching learn_hip m99/m100).
// EXACT R9 form. OUT_MODE: 0 fp32, 1 bf16, 2 bf16 transposed.
// ---------------------------------------------------------------------------
template <int OUT_MODE>
__device__ __forceinline__ void gemm_tile(const ushort* __restrict__ A,
                                          const ushort* __restrict__ Bt,
                                          void* __restrict__ Cv,
                                          int M, int N, int K, int bxi, int byi,
                                          ushort* As, ushort* Bs) {
  const int bm = byi * 128;
  const int bn = bxi * 128;
  const int tid  = threadIdx.x;
  const int lane = tid & 63;
  const int w    = tid >> 6;
  const int wr = w >> 1, wc = w & 1;
  const int lm = lane & 15, quad = lane >> 4;

  f32x4 acc[4][4];
#pragma unroll
  for (int i = 0; i < 4; ++i)
#pragma unroll
    for (int j = 0; j < 4; ++j) acc[i][j] = (f32x4){0.f, 0.f, 0.f, 0.f};

  for (int k0 = 0; k0 < K; k0 += 32) {
#pragma unroll
    for (int j = 0; j < 2; ++j) {
      int idx = j * 256 + tid;
      int row = idx >> 2;
      int col = (idx & 3) * 8;
      int ubase = (j * 256 + w * 64) * 8;
      async_copy16(A + (size_t)(bm + row) * K + k0 + col, &As[ubase]);
      async_copy16(Bt + (size_t)(bn + row) * K + k0 + col, &Bs[ubase]);
    }
    __syncthreads();
    short8 af[4], bfr[4];
#pragma unroll
    for (int t = 0; t < 4; ++t) {
      af[t]  = *(const short8*)&As[(wr * 64 + t * 16 + lm) * 32 + quad * 8];
      bfr[t] = *(const short8*)&Bs[(wc * 64 + t * 16 + lm) * 32 + quad * 8];
    }
#pragma unroll
    for (int i = 0; i < 4; ++i)
#pragma unroll
      for (int j = 0; j < 4; ++j)
        acc[i][j] = __builtin_amdgcn_mfma_f32_16x16x32_bf16(af[i], bfr[j], acc[i][j], 0, 0, 0);
    __syncthreads();
  }

#pragma unroll
  for (int i = 0; i < 4; ++i)
#pragma unroll
    for (int j = 0; j < 4; ++j) {
      if (OUT_MODE == 2) {
        int col  = bn + wc * 64 + j * 16 + lm;
        int rowb = bm + wr * 64 + i * 16 + quad * 4;
        ushort4 o4;
        o4.x = f2bf(acc[i][j][0]); o4.y = f2bf(acc[i][j][1]);
        o4.z = f2bf(acc[i][j][2]); o4.w = f2bf(acc[i][j][3]);
        *(ushort4*)&((ushort*)Cv)[(size_t)col * M + rowb] = o4;
      } else {
#pragma unroll
        for (int r = 0; r < 4; ++r) {
          size_t row = bm + wr * 64 + i * 16 + quad * 4 + r;
          size_t col = bn + wc * 64 + j * 16 + lm;
          if (OUT_MODE == 1) ((ushort*)Cv)[row * N + col] = f2bf(acc[i][j][r]);
          else               ((float*)Cv)[row * N + col]  = acc[i][j][r];
        }
      }
    }
}

__global__ __launch_bounds__(256) void gemm_qkv_kernel(const ushort* __restrict__ hb,
                                                       const ushort* __restrict__ wq,
                                                       const ushort* __restrict__ wk,
                                                       const ushort* __restrict__ wv,
                                                       ushort* __restrict__ qb,
                                                       ushort* __restrict__ kb,
                                                       ushort* __restrict__ vtb) {
  __shared__ __align__(16) ushort As[128 * 32];
  __shared__ __align__(16) ushort Bs[128 * 32];
  int bid = blockIdx.x;
  if (bid < 512) {
    gemm_tile<1>(hb, wq, qb, S, H * HD, D, bid & 15, bid >> 4, As, Bs);
  } else if (bid < 640) {
    int b = bid - 512;
    gemm_tile<1>(hb, wk, kb, S, KVH * HD, D, b & 3, b >> 2, As, Bs);
  } else {
    int b = bid - 640;
    gemm_tile<2>(hb, wv, vtb, S, KVH * HD, D, b & 3, b >> 2, As, Bs);
  }
}

template <int OUT_MODE>
__global__ __launch_bounds__(256) void gemm_bt_kernel(const ushort* __restrict__ A,
                                                      const ushort* __restrict__ Bt,
                                                      void* __restrict__ Cv,
                                                      int M, int N, int K) {
  __shared__ __align__(16) ushort As[128 * 32];
  __shared__ __align__(16) ushort Bs[128 * 32];
  gemm_tile<OUT_MODE>(A, Bt, Cv, M, N, K, blockIdx.x, blockIdx.y, As, Bs);
}

// R9-original standalone rope (all fusion placements measured worse: R10/R11/R12)
__global__ void rope_bf16_kernel(ushort* __restrict__ qb, ushort* __restrict__ kb,
                                 const int* __restrict__ pos_ids) {
  int idx = blockIdx.x * blockDim.x + threadIdx.x;
  const int total = S * (H + KVH) * (HD / 2);
  if (idx >= total) return;
  int j = idx & 63;
  int t = idx >> 6;
  int head = t % (H + KVH);
  int s = t / (H + KVH);
  float p = (float)pos_ids[s];
  float inv_freq = exp2f(-(float)j * (13.287712379549449f / 64.0f));
  float ang = p * inv_freq;
  float c = cosf(ang), sn = sinf(ang);
  ushort* base = (head < H) ? (qb + (size_t)s * (H * HD) + head * HD)
                            : (kb + (size_t)s * (KVH * HD) + (head - H) * HD);
  float x1 = bf2f(base[j]), x2 = bf2f(base[j + 64]);
  base[j]      = f2bf(x1 * c - x2 * sn);
  base[j + 64] = f2bf(x2 * c + x1 * sn);
}

// ---------------------------------------------------------------------------
// R13 attn: SMALL-LDS high-occupancy restructure of the R9 inner loop.
// Block = 256 thr = 4 waves = 4 q-groups (NO kv-parity); q-tile 128, kv-tile 32.
// Each wave owns q cols [q0+32w, +32) and the FULL kv range -> complete lsum
// per wave, direct store, no epilogue merge. LDS = 2 bufs x (K 8KB + V 8KB)
// = 32KB -> 5 blocks/CU capacity (vs R9's 64KB/512thr packing ~1.3/CU:
// measured R1/R5 = 41% of ceiling; 256thr/small-LDS GEMM blocks pack 7-8/CU).
// Grid doubled to 1024 via R5's correctness-PROVEN kv-split: lo tiles
// [0,2qi+2), hi [2qi+2,4qi+4); fixed-ref softmax partials add directly;
// Olo aliases d_out (fp32, exact size), Ohi+Ls in ws, attn_merge combines.
// LDS/pair economy preserved vs R9 (staged 4B/pair, frag reads 19.5B/pair --
// q-tile 128 is what keeps this; R4's q64 doubled it and lost).
// kvh-per-XCD pinning kept (R3: FETCH 30.7->16.4MB): h = 2*(bid&7)+((bid>>3)&1).
// permlane32_swap P-exchange kept (R7: -4.6us). Descending qi issue (LPT).
// ---------------------------------------------------------------------------
template <int SPLIT>
__global__ __launch_bounds__(256) void attn_mfma_kernel(const ushort* __restrict__ q,
                                                        const ushort* __restrict__ k,
                                                        const ushort* __restrict__ Vt,
                                                        ushort* __restrict__ o,
                                                        float* __restrict__ Olo,
                                                        float* __restrict__ Ohi,
                                                        float* __restrict__ Ls) {
  const int bid = blockIdx.x;
  const int h   = 2 * (bid & 7) + ((bid >> 3) & 1);   // kvh = h>>2 constant per XCD
  const int t   = bid >> 4;                 // SPLIT: 0..63, else 0..31
  const int half = SPLIT ? (t & 1) : 0;
  const int qi  = SPLIT ? (31 - (t >> 1)) : (31 - t); // descending work
  const int q0  = qi * 128;
  const int kvh = h >> 2;
  const int tid  = threadIdx.x;
  const int lane = tid & 63;
  const int w    = tid >> 6;                // 0..3 = q-group
  const int m32  = lane & 31;
  const int p    = lane >> 5;

  // [buf][K: 8 chunks x 512 | V: 8 chunks x 512] = 2 x 16KB = 32KB
  __shared__ __align__(16) ushort LDSu[16384];

  const int q0w = q0 + w * 32;

  // Q B-frags: B[n=q=lane&31][d=16s+8p+j]
  short8 qf[8];
#pragma unroll
  for (int s = 0; s < 8; ++s)
    qf[s] = *(const short8*)&q[(size_t)(q0w + m32) * (H * HD) + h * HD + s * 16 + p * 8];

  f32x16 Oacc[4];
#pragma unroll
  for (int i = 0; i < 4; ++i)
#pragma unroll
    for (int r = 0; r < 16; ++r) Oacc[i][r] = 0.f;
  float ls4[4] = {0.f, 0.f, 0.f, 0.f};      // 4 independent lsum chains

  // wave w stages chunks [4w, 4w+4): c<8 -> K chunk s=c, else V chunk cv=c-8
  auto stage = [&](int k0s, int buf) {
#pragma unroll
    for (int i = 0; i < 4; ++i) {
      int c = w * 4 + i;
      if (c < 8) {
        async_copy16(&k[(size_t)(k0s + m32) * (KVH * HD) + kvh * HD + c * 16 + p * 8],
                     &LDSu[buf * 8192 + c * 512]);
      } else {
        int cv = c - 8, ht = cv >> 1, t2 = cv & 1;
        async_copy16(&Vt[(size_t)(kvh * HD + ht * 32 + m32) * S + k0s + t2 * 16 + p * 8],
                     &LDSu[buf * 8192 + 4096 + cv * 512]);
      }
    }
  };

  const int T    = SPLIT ? (2 * qi + 2) : (4 * qi + 4);   // kv32 tiles this block
  const int koff = SPLIT ? (half * (2 * qi + 2)) : 0;

  stage(koff * 32, 0);
  __syncthreads();

  const float C1  = 0.08838834764831845f * 1.4426950408889634f;  // scale*log2e
  const float F2n = -12.0f * 1.4426950408889634f;                // -FM*log2e

  for (int tt = 0; tt < T; ++tt) {
    const int k0  = (koff + tt) * 32;
    const int cur = tt & 1;
    if (tt + 1 < T) stage(k0 + 32, cur ^ 1);
    const ushort* Kb = &LDSu[cur * 8192];
    const ushort* Vb = Kb + 4096;

    if (k0 <= q0w + 31) {                    // wave-uniform tile liveness
      // ---- S^T subtile (kv32 x q32): 8 MFMA, two independent chains ----
      f32x16 stA, stB;
#pragma unroll
      for (int r = 0; r < 16; ++r) { stA[r] = 0.f; stB[r] = 0.f; }
#pragma unroll
      for (int s = 0; s < 8; s += 2) {
        short8 kf0 = *(const short8*)&Kb[s * 512 + lane * 8];
        short8 kf1 = *(const short8*)&Kb[(s + 1) * 512 + lane * 8];
        stA = __builtin_amdgcn_mfma_f32_32x32x16_bf16(kf0, qf[s], stA, 0, 0, 0);
        stB = __builtin_amdgcn_mfma_f32_32x32x16_bf16(kf1, qf[s + 1], stB, 0, 0, 0);
      }

      // ---- softmax terms ----
      float pv[16];
      if (k0 == q0w) {                       // diagonal subtile: masked path
#pragma unroll
        for (int r = 0; r < 16; ++r) {
          int kvl = (r & 3) + 8 * (r >> 2) + 4 * p;
          float e = fast_exp2(fmaf(stA[r] + stB[r], C1, F2n));
          e = (kvl > m32) ? 0.f : e;
          pv[r] = e; ls4[r & 3] += e;
        }
      } else {                               // clean subtile: no compares
#pragma unroll
        for (int r = 0; r < 16; ++r) {
          float e = fast_exp2(fmaf(stA[r] + stB[r], C1, F2n));
          pv[r] = e; ls4[r & 3] += e;
        }
      }

      // ---- C-layout -> PV B-frag: pack + permlane32_swap (VALU, no DS) ----
      unsigned own2[4][2];
#pragma unroll
      for (int g = 0; g < 4; ++g) {
        own2[g][0] = pkbf_t(pv[4 * g + 0], pv[4 * g + 1]);
        own2[g][1] = pkbf_t(pv[4 * g + 2], pv[4 * g + 3]);
      }
      short8 pf[2];
#pragma unroll
      for (int t2 = 0; t2 < 2; ++t2) {
        unsigned x0, y0, x1, y1;
        swap_half(own2[2 * t2][0], own2[2 * t2 + 1][0], x0, y0);
        swap_half(own2[2 * t2][1], own2[2 * t2 + 1][1], x1, y1);
        union { unsigned u4[4]; short8 s8; } pb;
        pb.u4[0] = x0; pb.u4[1] = x1; pb.u4[2] = y0; pb.u4[3] = y1;
        pf[t2] = pb.s8;
      }

      // ---- O^T += V^T·P : 8 MFMA (4 independent ht chains) ----
#pragma unroll
      for (int ht = 0; ht < 4; ++ht)
#pragma unroll
        for (int t2l = 0; t2l < 2; ++t2l) {
          short8 vf = *(const short8*)&Vb[(ht * 2 + t2l) * 512 + lane * 8];
          Oacc[ht] = __builtin_amdgcn_mfma_f32_32x32x16_bf16(vf, pf[t2l], Oacc[ht], 0, 0, 0);
        }
    }
    __syncthreads();
  }

  // ---- epilogue: each wave has COMPLETE (Oacc, lsum) for its q32 rows ----
  float lsum = (ls4[0] + ls4[1]) + (ls4[2] + ls4[3]);
  float ltot = lsum + __shfl_xor(lsum, 32);

  if (SPLIT) {
    // unnormalized fp32 partial + per-row lsum; merged by attn_merge_kernel
    float* Od = half ? Ohi : Olo;
    size_t rb = (size_t)(q0w + m32) * (H * HD) + h * HD;
#pragma unroll
    for (int ht = 0; ht < 4; ++ht)
#pragma unroll
      for (int rq = 0; rq < 4; ++rq) {
        float4 v;
        v.x = Oacc[ht][4 * rq + 0]; v.y = Oacc[ht][4 * rq + 1];
        v.z = Oacc[ht][4 * rq + 2]; v.w = Oacc[ht][4 * rq + 3];
        *(float4*)&Od[rb + ht * 32 + 8 * rq + 4 * p] = v;
      }
    if (lane < 32) Ls[(size_t)(half * 16 + h) * S + q0w + m32] = ltot;
  } else {
    float inv = 1.0f / ltot;
#pragma unroll
    for (int ht = 0; ht < 4; ++ht)
#pragma unroll
      for (int rq = 0; rq < 4; ++rq) {
        uint2 dd;
        dd.x = pkbf(Oacc[ht][4 * rq + 0] * inv, Oacc[ht][4 * rq + 1] * inv);
        dd.y = pkbf(Oacc[ht][4 * rq + 2] * inv, Oacc[ht][4 * rq + 3] * inv);
        *(uint2*)&o[(size_t)(q0w + m32) * (H * HD) + h * HD + ht * 32 + 8 * rq + 4 * p] = dd;
      }
  }
}

// ---------------------------------------------------------------------------
// merge lo/hi kv-half partials: ob = (Olo + Ohi) / (Llo + Lhi), bf16
// (R5-proven correct, verbatim)
// ---------------------------------------------------------------------------
__global__ __launch_bounds__(256) void attn_merge_kernel(const float* __restrict__ Olo,
                                                         const float* __restrict__ Ohi,
                                                         const float* __restrict__ Ls,
                                                         ushort* __restrict__ ob) {
  size_t i4 = ((size_t)blockIdx.x * 256 + threadIdx.x) * 4;
  int s = (int)(i4 >> 11);                  // row (H*HD = 2048 per row)
  int h = ((int)i4 & 2047) >> 7;
  float inv = 1.0f / (Ls[(size_t)h * S + s] + Ls[(size_t)(16 + h) * S + s]);
  float4 a = *(const float4*)&Olo[i4];
  float4 b = *(const float4*)&Ohi[i4];
  uint2 dd;
  dd.x = pkbf((a.x + b.x) * inv, (a.y + b.y) * inv);
  dd.y = pkbf((a.z + b.z) * inv, (a.w + b.w) * inv);
  *(uint2*)&ob[i4] = dd;
}

// ---------------------------------------------------------------------------
// cvt(1) -> QKV proj(1) -> RoPE(1) -> kv-split flash attn(1) -> merge(1)
// -> O proj(1)
// ---------------------------------------------------------------------------
extern "C" void kernel_launch(void* const* d_in, const int* in_sizes, int n_in,
                              void* d_out, int out_size, void* d_ws, size_t ws_size,
                              hipStream_t stream) {
  const float* hidden = (const float*)d_in[0];
  const float* Wq     = (const float*)d_in[1];
  const float* Wk     = (const float*)d_in[2];
  const float* Wv     = (const float*)d_in[3];
  const float* Wo     = (const float*)d_in[4];
  const int*   pos    = (const int*)d_in[5];
  float* out = (float*)d_out;

  ushort* hb  = (ushort*)d_ws;
  ushort* wqb = hb  + N_HID;
  ushort* wkb = wqb + N_WQ;
  ushort* wvb = wkb + N_WKV;
  ushort* wob = wvb + N_WKV;
  ushort* qb  = wob + N_WQ;
  ushort* kb  = qb  + (size_t)S * (H * HD);
  ushort* vtb = kb  + (size_t)S * (KVH * HD);
  ushort* ob  = vtb + (size_t)(KVH * HD) * S;
  // kv-split partials: Olo aliases d_out (fp32, exactly out_size);
  // Ohi + Ls appended to ws after ob (R5-proven headroom).
  float* Olo = (float*)d_out;
  float* Ohi = (float*)(ob + (size_t)S * (H * HD));
  float* Ls  = Ohi + (size_t)S * (H * HD);
  size_t ws_need = (size_t)((char*)(Ls + (size_t)2 * H * S) - (char*)d_ws);
  bool split = ws_size >= ws_need;

  dim3 blk(256);
  size_t n4 = C5_ / 4;
  cvt_all_kernel<<<(int)((n4 + 255) / 256), blk, 0, stream>>>(hidden, Wq, Wk, Wv, Wo, hb);

  gemm_qkv_kernel<<<dim3(768), blk, 0, stream>>>(hb, wqb, wkb, wvb, qb, kb, vtb);

  int rope_total = S * (H + KVH) * (HD / 2);
  rope_bf16_kernel<<<(rope_total + 255) / 256, blk, 0, stream>>>(qb, kb, pos);

  if (split) {
    attn_mfma_kernel<1><<<dim3(1024), blk, 0, stream>>>(qb, kb, vtb, ob, Olo, Ohi, Ls);
    attn_merge_kernel<<<dim3((int)((size_t)S * H * HD / 4 / 256)), blk, 0, stream>>>(Olo, Ohi, Ls, ob);
  } else {
    attn_mfma_kernel<0><<<dim3(512), blk, 0, stream>>>(qb, kb, vtb, ob, Olo, Ohi, Ls);
  }

  gemm_bt_kernel<0><<<dim3(D / 128, S / 128), blk, 0, stream>>>(ob, wob, out, S, D, D);
}

// Round 14
// 343.270 us; speedup vs baseline: 1.0830x; 1.0830x over previous
//
#include <hip/hip_runtime.h>
#include <hip/hip_bf16.h>

constexpr int S   = 4096;
constexpr int D   = 2048;
constexpr int H   = 16;
constexpr int KVH = 4;
constexpr int HD  = 128;

using short8 = __attribute__((ext_vector_type(8))) short;
using f32x4  = __attribute__((ext_vector_type(4))) float;
using f32x16 = __attribute__((ext_vector_type(16))) float;

__device__ inline ushort f2bf(float f) {
  union { float f; unsigned u; } x{f};
  unsigned r = x.u + 0x7FFFu + ((x.u >> 16) & 1u);
  return (ushort)(r >> 16);
}
__device__ inline float bf2f(ushort h) {
  union { unsigned u; float f; } x{(unsigned)h << 16};
  return x.f;
}
// RNE pack: two floats -> bf16x2
__device__ inline unsigned pkbf(float a, float b) {
  union { float f; unsigned u; } xa{a}, xb{b};
  unsigned ra = xa.u + 0x7FFFu + ((xa.u >> 16) & 1u);
  unsigned rb = xb.u + 0x7FFFu + ((xb.u >> 16) & 1u);
#if __has_builtin(__builtin_amdgcn_perm)
  return __builtin_amdgcn_perm(rb, ra, 0x07060302u);
#else
  return (rb & 0xFFFF0000u) | (ra >> 16);
#endif
}
// truncating pack (1 VALU op): for P values in [0,1] feeding PV; ~0.2% downward bias
__device__ inline unsigned pkbf_t(float a, float b) {
  union { float f; unsigned u; } xa{a}, xb{b};
#if __has_builtin(__builtin_amdgcn_perm)
  return __builtin_amdgcn_perm(xb.u, xa.u, 0x07060302u);
#else
  return (xb.u & 0xFFFF0000u) | (xa.u >> 16);
#endif
}
__device__ inline float fast_exp2(float x) {
#if __has_builtin(__builtin_amdgcn_exp2f)
  return __builtin_amdgcn_exp2f(x);
#else
  return exp2f(x);
#endif
}

// lane i<->i+32 half exchange, one VALU op for TWO outputs:
// x = {a_lo, b_lo}, y = {a_hi, b_hi}  (verified correct by R6/R7/R9 harness passes)
__device__ inline void swap_half(unsigned a, unsigned b, unsigned& x, unsigned& y) {
#if __has_builtin(__builtin_amdgcn_permlane32_swap)
  using uint2v = __attribute__((ext_vector_type(2))) unsigned;
  uint2v r = __builtin_amdgcn_permlane32_swap(a, b, false, false);
  x = r[0]; y = r[1];
#else
  unsigned bx = __shfl_xor(b, 32), ax = __shfl_xor(a, 32);
  int p = (threadIdx.x & 63) >> 5;
  x = p ? bx : a;
  y = p ? b : ax;
#endif
}

__device__ inline void async_copy16(const ushort* g, ushort* l) {
  __builtin_amdgcn_global_load_lds(
      (const __attribute__((address_space(1))) unsigned int*)g,
      (__attribute__((address_space(3))) unsigned int*)l, 16, 0, 0);
}

// ---------------------------------------------------------------------------
// Fused fp32->bf16 convert (dst segments contiguous in ws)
// ---------------------------------------------------------------------------
constexpr size_t N_HID = (size_t)S * D;
constexpr size_t N_WQ  = (size_t)(H * HD) * D;
constexpr size_t N_WKV = (size_t)(KVH * HD) * D;
constexpr size_t C1_ = N_HID;
constexpr size_t C2_ = C1_ + N_WQ;
constexpr size_t C3_ = C2_ + N_WKV;
constexpr size_t C4_ = C3_ + N_WKV;
constexpr size_t C5_ = C4_ + N_WQ;

__global__ void cvt_all_kernel(const float* __restrict__ hid, const float* __restrict__ wq,
                               const float* __restrict__ wk, const float* __restrict__ wv,
                               const float* __restrict__ wo, ushort* __restrict__ dst) {
  size_t i = (size_t)blockIdx.x * blockDim.x + threadIdx.x;
  size_t off = i * 4;
  if (off >= C5_) return;
  const float* src;
  if      (off < C1_) src = hid + off;
  else if (off < C2_) src = wq + (off - C1_);
  else if (off < C3_) src = wk + (off - C2_);
  else if (off < C4_) src = wv + (off - C3_);
  else                src = wo + (off - C4_);
  float4 f = *(const float4*)src;
  ushort4 o;
  o.x = f2bf(f.x); o.y = f2bf(f.y); o.z = f2bf(f.z); o.w = f2bf(f.w);
  *(ushort4*)&dst[off] = o;
}

// ---------------------------------------------------------------------------
// bf16 MFMA GEMM tile (NT), m97 recipe — SINGLE-buffered (R3/R0 form; R7
// proved explicit dbuf regresses this structure, matching learn_hip m99/m100).
// EXACT R9 form. OUT_MODE: 0 fp32, 1 bf16, 2 bf16 transposed.
// ---------------------------------------------------------------------------
template <int OUT_MODE>
__device__ __forceinline__ void gemm_tile(const ushort* __restrict__ A,
                                          const ushort* __restrict__ Bt,
                                          void* __restrict__ Cv,
                                          int M, int N, int K, int bxi, int byi,
                                          ushort* As, ushort* Bs) {
  const int bm = byi * 128;
  const int bn = bxi * 128;
  const int tid  = threadIdx.x;
  const int lane = tid & 63;
  const int w    = tid >> 6;
  const int wr = w >> 1, wc = w & 1;
  const int lm = lane & 15, quad = lane >> 4;

  f32x4 acc[4][4];
#pragma unroll
  for (int i = 0; i < 4; ++i)
#pragma unroll
    for (int j = 0; j < 4; ++j) acc[i][j] = (f32x4){0.f, 0.f, 0.f, 0.f};

  for (int k0 = 0; k0 < K; k0 += 32) {
#pragma unroll
    for (int j = 0; j < 2; ++j) {
      int idx = j * 256 + tid;
      int row = idx >> 2;
      int col = (idx & 3) * 8;
      int ubase = (j * 256 + w * 64) * 8;
      async_copy16(A + (size_t)(bm + row) * K + k0 + col, &As[ubase]);
      async_copy16(Bt + (size_t)(bn + row) * K + k0 + col, &Bs[ubase]);
    }
    __syncthreads();
    short8 af[4], bfr[4];
#pragma unroll
    for (int t = 0; t < 4; ++t) {
      af[t]  = *(const short8*)&As[(wr * 64 + t * 16 + lm) * 32 + quad * 8];
      bfr[t] = *(const short8*)&Bs[(wc * 64 + t * 16 + lm) * 32 + quad * 8];
    }
#pragma unroll
    for (int i = 0; i < 4; ++i)
#pragma unroll
      for (int j = 0; j < 4; ++j)
        acc[i][j] = __builtin_amdgcn_mfma_f32_16x16x32_bf16(af[i], bfr[j], acc[i][j], 0, 0, 0);
    __syncthreads();
  }

#pragma unroll
  for (int i = 0; i < 4; ++i)
#pragma unroll
    for (int j = 0; j < 4; ++j) {
      if (OUT_MODE == 2) {
        int col  = bn + wc * 64 + j * 16 + lm;
        int rowb = bm + wr * 64 + i * 16 + quad * 4;
        ushort4 o4;
        o4.x = f2bf(acc[i][j][0]); o4.y = f2bf(acc[i][j][1]);
        o4.z = f2bf(acc[i][j][2]); o4.w = f2bf(acc[i][j][3]);
        *(ushort4*)&((ushort*)Cv)[(size_t)col * M + rowb] = o4;
      } else {
#pragma unroll
        for (int r = 0; r < 4; ++r) {
          size_t row = bm + wr * 64 + i * 16 + quad * 4 + r;
          size_t col = bn + wc * 64 + j * 16 + lm;
          if (OUT_MODE == 1) ((ushort*)Cv)[row * N + col] = f2bf(acc[i][j][r]);
          else               ((float*)Cv)[row * N + col]  = acc[i][j][r];
        }
      }
    }
}

__global__ __launch_bounds__(256) void gemm_qkv_kernel(const ushort* __restrict__ hb,
                                                       const ushort* __restrict__ wq,
                                                       const ushort* __restrict__ wk,
                                                       const ushort* __restrict__ wv,
                                                       ushort* __restrict__ qb,
                                                       ushort* __restrict__ kb,
                                                       ushort* __restrict__ vtb) {
  __shared__ __align__(16) ushort As[128 * 32];
  __shared__ __align__(16) ushort Bs[128 * 32];
  int bid = blockIdx.x;
  if (bid < 512) {
    gemm_tile<1>(hb, wq, qb, S, H * HD, D, bid & 15, bid >> 4, As, Bs);
  } else if (bid < 640) {
    int b = bid - 512;
    gemm_tile<1>(hb, wk, kb, S, KVH * HD, D, b & 3, b >> 2, As, Bs);
  } else {
    int b = bid - 640;
    gemm_tile<2>(hb, wv, vtb, S, KVH * HD, D, b & 3, b >> 2, As, Bs);
  }
}

template <int OUT_MODE>
__global__ __launch_bounds__(256) void gemm_bt_kernel(const ushort* __restrict__ A,
                                                      const ushort* __restrict__ Bt,
                                                      void* __restrict__ Cv,
                                                      int M, int N, int K) {
  __shared__ __align__(16) ushort As[128 * 32];
  __shared__ __align__(16) ushort Bs[128 * 32];
  gemm_tile<OUT_MODE>(A, Bt, Cv, M, N, K, blockIdx.x, blockIdx.y, As, Bs);
}

// R9-original standalone rope (all fusion placements measured worse: R10/R11/R12)
__global__ void rope_bf16_kernel(ushort* __restrict__ qb, ushort* __restrict__ kb,
                                 const int* __restrict__ pos_ids) {
  int idx = blockIdx.x * blockDim.x + threadIdx.x;
  const int total = S * (H + KVH) * (HD / 2);
  if (idx >= total) return;
  int j = idx & 63;
  int t = idx >> 6;
  int head = t % (H + KVH);
  int s = t / (H + KVH);
  float p = (float)pos_ids[s];
  float inv_freq = exp2f(-(float)j * (13.287712379549449f / 64.0f));
  float ang = p * inv_freq;
  float c = cosf(ang), sn = sinf(ang);
  ushort* base = (head < H) ? (qb + (size_t)s * (H * HD) + head * HD)
                            : (kb + (size_t)s * (KVH * HD) + (head - H) * HD);
  float x1 = bf2f(base[j]), x2 = bf2f(base[j + 64]);
  base[j]      = f2bf(x1 * c - x2 * sn);
  base[j + 64] = f2bf(x2 * c + x1 * sn);
}

// ---------------------------------------------------------------------------
// Transposed-flow bf16 MFMA causal flash attention (32x32x16), frag-major LDS.
// EXACT R9 attn kernel (114.6 us best-measured) + ONE isolated change:
// s_setprio(1) around the two MFMA clusters (T5, m191 regime: 2 independent
// blocks/CU, no cross-block sync -> scheduler can favor MFMA-phase waves).
// [R13 lesson: occupancy is pinned ~20% across ALL structures (5 tried);
//  scheduling/packing axis permanently closed. R2's setprio was confounded
//  with 2 other bad changes -- this is the clean isolation.]
//  - kvh-per-XCD pinning (R3: FETCH 30.7 -> 16.4 MB)
//  - P lane^32 exchange via v_permlane32_swap (R7: -4.6 us vs ds_bpermute)
// [R6 lesson: V must stay LDS-staged; direct global V-frags = 64-line scatter.]
// Block = 512 thr = 8 waves = 4 q-groups x 2 kv-parities; q-tile 128; kv 64.
// Grid 512, descending qi; XCD = bid%8, h = 2*(bid&7)+((bid>>3)&1).
// ---------------------------------------------------------------------------
__global__ __launch_bounds__(512) void attn_mfma_kernel(const ushort* __restrict__ q,
                                                        const ushort* __restrict__ k,
                                                        const ushort* __restrict__ Vt,
                                                        ushort* __restrict__ o) {
  const int bid = blockIdx.x;
  const int h   = 2 * (bid & 7) + ((bid >> 3) & 1);   // kvh = h>>2 constant per XCD
  const int t   = bid >> 4;                 // 0..31
  const int qi  = 31 - t;                   // descending work order
  const int q0  = qi * 128;
  const int kvh = h >> 2;
  const int tid  = threadIdx.x;
  const int lane = tid & 63;
  const int w    = tid >> 6;                // 0..7
  const int qw   = w >> 1;                  // q-group 0..3
  const int ks   = w & 1;                   // kv parity 0..1
  const int m32  = lane & 31;
  const int p    = lane >> 5;

  // [buf][K: 16 chunks x 512] at 0 / [buf][V: 16 chunks x 512] at 16384
  __shared__ __align__(16) ushort LDSu[32768];

  const int q0w = q0 + qw * 32;

  // Q B-frags: B[n=q=lane&31][d=16s+8p+j]
  short8 qf[8];
#pragma unroll
  for (int s = 0; s < 8; ++s)
    qf[s] = *(const short8*)&q[(size_t)(q0w + m32) * (H * HD) + h * HD + s * 16 + p * 8];

  f32x16 Oacc[4];
#pragma unroll
  for (int i = 0; i < 4; ++i)
#pragma unroll
    for (int r = 0; r < 16; ++r) Oacc[i][r] = 0.f;
  float ls4[4] = {0.f, 0.f, 0.f, 0.f};      // 4 independent lsum chains

  // wave w stages chunks [4w, 4w+4): waves 0-3 -> K, waves 4-7 -> V
  auto stage = [&](int k0s, int buf) {
#pragma unroll
    for (int i = 0; i < 4; ++i) {
      int c = w * 4 + i;
      if (c < 16) {
        int kh = c >> 3, s = c & 7;
        async_copy16(&k[(size_t)(k0s + kh * 32 + m32) * (KVH * HD) + kvh * HD + s * 16 + p * 8],
                     &LDSu[buf * 8192 + c * 512]);
      } else {
        int cv = c - 16;
        int ht = cv >> 2, t2 = cv & 3;
        async_copy16(&Vt[(size_t)(kvh * HD + ht * 32 + m32) * S + k0s + t2 * 16 + p * 8],
                     &LDSu[16384 + buf * 8192 + cv * 512]);
      }
    }
  };

  stage(0, 0);
  __syncthreads();

  const float C1  = 0.08838834764831845f * 1.4426950408889634f;  // scale*log2e
  const float F2n = -12.0f * 1.4426950408889634f;                // -FM*log2e
  const int T = 2 * qi + 2;

  for (int tt = 0; tt < T; ++tt) {
    const int k0  = tt * 64;
    const int cur = tt & 1;
    if (tt + 1 < T) stage(k0 + 64, cur ^ 1);
    const ushort* Kb = &LDSu[cur * 8192];
    const ushort* Vb = &LDSu[16384 + cur * 8192];

    const int kbase = k0 + ks * 32;          // this wave's kv-subtile
    if (kbase <= q0w + 31) {                 // wave-uniform subtile liveness
      // ---- S^T subtile: 8 MFMA, two independent chains ----
      f32x16 stA, stB;
#pragma unroll
      for (int r = 0; r < 16; ++r) { stA[r] = 0.f; stB[r] = 0.f; }
      __builtin_amdgcn_s_setprio(1);
#pragma unroll
      for (int s = 0; s < 8; s += 2) {
        short8 kf0 = *(const short8*)&Kb[(ks * 8 + s) * 512 + lane * 8];
        short8 kf1 = *(const short8*)&Kb[(ks * 8 + s + 1) * 512 + lane * 8];
        stA = __builtin_amdgcn_mfma_f32_32x32x16_bf16(kf0, qf[s], stA, 0, 0, 0);
        stB = __builtin_amdgcn_mfma_f32_32x32x16_bf16(kf1, qf[s + 1], stB, 0, 0, 0);
      }
      __builtin_amdgcn_s_setprio(0);

      // ---- softmax terms ----
      float pv[16];
      if (kbase == q0w) {                    // diagonal subtile: masked path
#pragma unroll
        for (int r = 0; r < 16; ++r) {
          int kvl = (r & 3) + 8 * (r >> 2) + 4 * p;
          float e = fast_exp2(fmaf(stA[r] + stB[r], C1, F2n));
          e = (kvl > m32) ? 0.f : e;
          pv[r] = e; ls4[r & 3] += e;
        }
      } else {                               // clean subtile: no compares
#pragma unroll
        for (int r = 0; r < 16; ++r) {
          float e = fast_exp2(fmaf(stA[r] + stB[r], C1, F2n));
          pv[r] = e; ls4[r & 3] += e;
        }
      }

      // ---- C-layout -> PV B-frag: pack + permlane32_swap (VALU, no DS) ----
      unsigned own2[4][2];
#pragma unroll
      for (int g = 0; g < 4; ++g) {
        own2[g][0] = pkbf_t(pv[4 * g + 0], pv[4 * g + 1]);
        own2[g][1] = pkbf_t(pv[4 * g + 2], pv[4 * g + 3]);
      }
      short8 pf[2];
#pragma unroll
      for (int t2 = 0; t2 < 2; ++t2) {
        unsigned x0, y0, x1, y1;
        swap_half(own2[2 * t2][0], own2[2 * t2 + 1][0], x0, y0);
        swap_half(own2[2 * t2][1], own2[2 * t2 + 1][1], x1, y1);
        union { unsigned u4[4]; short8 s8; } pb;
        pb.u4[0] = x0; pb.u4[1] = x1; pb.u4[2] = y0; pb.u4[3] = y1;
        pf[t2] = pb.s8;
      }

      // ---- O^T += V^T·P : 8 MFMA (4 independent ht chains) ----
      __builtin_amdgcn_s_setprio(1);
#pragma unroll
      for (int ht = 0; ht < 4; ++ht)
#pragma unroll
        for (int t2l = 0; t2l < 2; ++t2l) {
          int cv = ht * 4 + ks * 2 + t2l;
          short8 vf = *(const short8*)&Vb[cv * 512 + lane * 8];
          Oacc[ht] = __builtin_amdgcn_mfma_f32_32x32x16_bf16(vf, pf[t2l], Oacc[ht], 0, 0, 0);
        }
      __builtin_amdgcn_s_setprio(0);
    }
    __syncthreads();
  }

  // ---- epilogue: merge kv-parity partners through LDS, then store ----
  float lsum = (ls4[0] + ls4[1]) + (ls4[2] + ls4[3]);
  float* mb = (float*)LDSu;                  // 16384 floats, loop is done with LDS

  // phase 1: lsum exchange (ks=1 -> ks=0)
  if (ks) mb[(qw << 6) | lane] = lsum;
  __syncthreads();
  if (!ks) lsum += mb[(qw << 6) | lane];
  __syncthreads();

  // phase 2: Oacc exchange, conflict-free [r][lane] layout (stride 4B)
  if (ks) {
    float* base = mb + qw * 4096;
#pragma unroll
    for (int ht = 0; ht < 4; ++ht)
#pragma unroll
      for (int r = 0; r < 16; ++r)
        base[ht * 1024 + r * 64 + lane] = Oacc[ht][r];
  }
  __syncthreads();

  if (!ks) {
    const float* base = mb + qw * 4096;
#pragma unroll
    for (int ht = 0; ht < 4; ++ht)
#pragma unroll
      for (int r = 0; r < 16; ++r)
        Oacc[ht][r] += base[ht * 1024 + r * 64 + lane];

    float ltot = lsum + __shfl_xor(lsum, 32);
    float inv = 1.0f / ltot;
#pragma unroll
    for (int ht = 0; ht < 4; ++ht)
#pragma unroll
      for (int rq = 0; rq < 4; ++rq) {
        uint2 dd;
        dd.x = pkbf(Oacc[ht][4 * rq + 0] * inv, Oacc[ht][4 * rq + 1] * inv);
        dd.y = pkbf(Oacc[ht][4 * rq + 2] * inv, Oacc[ht][4 * rq + 3] * inv);
        *(uint2*)&o[(size_t)(q0w + m32) * (H * HD) + h * HD + ht * 32 + 8 * rq + 4 * p] = dd;
      }
  }
}

// ---------------------------------------------------------------------------
// cvt(1) -> fused QKV proj(1) -> RoPE(1) -> flash attn(1) -> O proj(1)
// ---------------------------------------------------------------------------
extern "C" void kernel_launch(void* const* d_in, const int* in_sizes, int n_in,
                              void* d_out, int out_size, void* d_ws, size_t ws_size,
                              hipStream_t stream) {
  const float* hidden = (const float*)d_in[0];
  const float* Wq     = (const float*)d_in[1];
  const float* Wk     = (const float*)d_in[2];
  const float* Wv     = (const float*)d_in[3];
  const float* Wo     = (const float*)d_in[4];
  const int*   pos    = (const int*)d_in[5];
  float* out = (float*)d_out;

  ushort* hb  = (ushort*)d_ws;
  ushort* wqb = hb  + N_HID;
  ushort* wkb = wqb + N_WQ;
  ushort* wvb = wkb + N_WKV;
  ushort* wob = wvb + N_WKV;
  ushort* qb  = wob + N_WQ;
  ushort* kb  = qb  + (size_t)S * (H * HD);
  ushort* vtb = kb  + (size_t)S * (KVH * HD);
  ushort* ob  = vtb + (size_t)(KVH * HD) * S;

  dim3 blk(256);
  size_t n4 = C5_ / 4;
  cvt_all_kernel<<<(int)((n4 + 255) / 256), blk, 0, stream>>>(hidden, Wq, Wk, Wv, Wo, hb);

  gemm_qkv_kernel<<<dim3(768), blk, 0, stream>>>(hb, wqb, wkb, wvb, qb, kb, vtb);

  int rope_total = S * (H + KVH) * (HD / 2);
  rope_bf16_kernel<<<(rope_total + 255) / 256, blk, 0, stream>>>(qb, kb, pos);

  attn_mfma_kernel<<<dim3(512), dim3(512), 0, stream>>>(qb, kb, vtb, ob);

  gemm_bt_kernel<0><<<dim3(D / 128, S / 128), blk, 0, stream>>>(ob, wob, out, S, D, D);
}